// Round 15
// baseline (100.989 us; speedup 1.0000x reference)
//
#include <hip/hip_runtime.h>
#include <math.h>

#define TLEN 7680
#define NB 384
#define NW 6          // waves per block
#define CHUNK 20      // TLEN / NB ; CHUNK > DIST-1=19 => window spans <=1 neighbor chunk
#define KMAX 386      // T//DIST + 2

// DPP cross-lane (VALU pipe, not LDS)
template<int CTRL>
__device__ __forceinline__ float dpp_xfer(float v){
  return __builtin_bit_cast(float, __builtin_amdgcn_update_dpp(
      0, __builtin_bit_cast(int, v), CTRL, 0xF, 0xF, true));
}
// Full 6-level wave64 reduction on pure DPP; RESULT VALID IN LANE 63 ONLY.
__device__ __forceinline__ float wsum(float v){
  v += dpp_xfer<0xB1>(v);
  v += dpp_xfer<0x4E>(v);
  v += dpp_xfer<0x141>(v);
  v += dpp_xfer<0x140>(v);
  v += dpp_xfer<0x142>(v);
  v += dpp_xfer<0x143>(v);
  return v;
}
__device__ __forceinline__ float wmaxr(float v){
  v = fmaxf(v, dpp_xfer<0xB1>(v));
  v = fmaxf(v, dpp_xfer<0x4E>(v));
  v = fmaxf(v, dpp_xfer<0x141>(v));
  v = fmaxf(v, dpp_xfer<0x140>(v));
  v = fmaxf(v, dpp_xfer<0x142>(v));
  v = fmaxf(v, dpp_xfer<0x143>(v));
  return v;
}
__device__ __forceinline__ float wminr(float v){
  v = fminf(v, dpp_xfer<0xB1>(v));
  v = fminf(v, dpp_xfer<0x4E>(v));
  v = fminf(v, dpp_xfer<0x141>(v));
  v = fminf(v, dpp_xfer<0x140>(v));
  v = fminf(v, dpp_xfer<0x142>(v));
  v = fminf(v, dpp_xfer<0x143>(v));
  return v;
}
// hardware trig, input in revolutions in [0,1): D = sin/cos(2*pi*S0)
__device__ __forceinline__ float hw_sin_rev(float t){
  float r; asm("v_sin_f32 %0, %1" : "=v"(r) : "v"(t)); return r;
}
__device__ __forceinline__ float hw_cos_rev(float t){
  float r; asm("v_cos_f32 %0, %1" : "=v"(r) : "v"(t)); return r;
}

__global__ __launch_bounds__(NB, 4)
void bvp_feat_kernel(const float* __restrict__ x, float* __restrict__ out, int B){
  const int tid = threadIdx.x;
  const int lane = tid & 63;
  const int w = tid >> 6;
  const int row0 = blockIdx.x * 2;

  __shared__ __align__(16) float s_bvp[TLEN];
  __shared__ __align__(16) float s_pad[CHUNK];   // -INF dummy halo chunk
  __shared__ __align__(16) float s_rri[384];     // dedicated (not aliased)
  __shared__ unsigned short s_tbl[384];
  __shared__ unsigned short s_pk[KMAX];
  __shared__ float s_red[17][NW];
  __shared__ int   s_wtot[NW];
  __shared__ float s_pw[46];
  __shared__ float s_rf[10];
  __shared__ float s_stash[16];

  const float INVFS = 1.0f/64.0f;
  const int base = tid * CHUNK;
  if (tid < CHUNK) s_pad[tid] = -INFINITY;

  // ---- prologue: load row0 -> regs, moments, stage to LDS ----
  float v[CHUNK];
  float m1=0.f,m2=0.f,m3=0.f,m4=0.f,vmn=INFINITY,vmx=-INFINITY;
  {
    const float4* src4 = (const float4*)(x + (size_t)row0 * TLEN + base);
    float4* dst4 = (float4*)(s_bvp + base);
#pragma unroll
    for (int q = 0; q < 5; ++q){
      float4 t4 = src4[q];
      dst4[q] = t4;
      v[4*q+0]=t4.x; v[4*q+1]=t4.y; v[4*q+2]=t4.z; v[4*q+3]=t4.w;
    }
#pragma unroll
    for (int j = 0; j < CHUNK; ++j){
      float a = v[j]; float q = a*a;
      m1 += a; m2 += q; m3 += q*a; m4 += q*q;
      vmn = fminf(vmn, a); vmx = fmaxf(vmx, a);
    }
  }
  __syncthreads();   // [B0]

  float4 vn4[5];
  float n1=0.f,n2=0.f,n3=0.f,n4=0.f,nmn=INFINITY,nmx=-INFINITY;

#pragma unroll
  for (int it = 0; it < 2; ++it){
    const int row = row0 + it;
    if (row >= B) break;                      // uniform
    const bool pre = (it == 0) && (row + 1 < B);

    // ---- P1: peak detection (v[] in regs; halos from LDS; M = pre-reduction vmx) ----
    const bool has_prev = (tid > 0);
    const bool has_next = (tid < NB-1);
    const float4* nb4 = has_next ? (const float4*)(s_bvp + base + CHUNK) : (const float4*)s_pad;
    const float4* pb4 = has_prev ? (const float4*)(s_bvp + base - CHUNK) : (const float4*)s_pad;
    const float prevs0 = has_prev ? s_bvp[base-1]     : INFINITY;
    const float next0  = has_next ? s_bvp[base+CHUNK] : INFINITY;
    const float M = vmx;

    unsigned cmask = 0u;
    {
      float pn = M;        // folds "cur >= own-chunk max" into rolling max
      float4 nq;
#pragma unroll
      for (int o = 0; o < CHUNK; ++o){
        if (o >= 1){
          const int j = o - 1;
          if ((j & 3) == 0) nq = nb4[j >> 2];
          float nv = ((j&3)==0) ? nq.x : ((j&3)==1) ? nq.y : ((j&3)==2) ? nq.z : nq.w;
          pn = fmaxf(pn, nv);
        }
        float cur = v[o];
        float prevs = (o == 0) ? prevs0 : v[o-1];
        float nxts  = (o == CHUNK-1) ? next0 : v[o+1];
        if (cur > prevs && cur > nxts && cur >= pn)
          cmask |= (1u << o);
      }
    }
    unsigned pmask = 0u;
    int pcnt = 0;
    {
      float sp = -INFINITY;
      float4 pq;
#pragma unroll
      for (int o = CHUNK-1; o >= 0; --o){
        if (((cmask >> o) & 1u) && (v[o] >= sp)){ pmask |= (1u << o); ++pcnt; }
        if (o > 0){
          if ((o & 3) == 3 || o == CHUNK-1) pq = pb4[o >> 2];
          float pv = ((o&3)==0) ? pq.x : ((o&3)==1) ? pq.y : ((o&3)==2) ? pq.z : pq.w;
          sp = fmaxf(sp, pv);
        }
      }
    }

    // wave shuffle scan
    int scan = pcnt;
#pragma unroll
    for (int off = 1; off < 64; off <<= 1){
      int t = __shfl_up(scan, off);
      if (lane >= off) scan += t;
    }
    if (lane == 63) s_wtot[w] = scan;
    __syncthreads();   // [B1]

    // ---- P2: compact peaks + amp partials + 8 block-wide reductions ----
    int wbase = 0, total = 0;
#pragma unroll
    for (int j = 0; j < NW; ++j){ if (j < w) wbase += s_wtot[j]; total += s_wtot[j]; }
    const int npk = total < KMAX ? total : KMAX;
    {
      float samp_p = 0.f, samp2_p = 0.f;
      int pos = wbase + scan - pcnt;
      unsigned mm = pmask;
      while (mm){
        int o = __ffs(mm) - 1;
        mm &= mm - 1u;
        if (pos < KMAX){
          s_pk[pos] = (unsigned short)(base + o);
          float a = v[o];
          samp_p += a; samp2_p += a*a;
        }
        ++pos;
      }
      m1 = wsum(m1); m2 = wsum(m2); m3 = wsum(m3); m4 = wsum(m4);
      vmn = wminr(vmn); vmx = wmaxr(vmx);
      samp_p = wsum(samp_p); samp2_p = wsum(samp2_p);
      if (lane == 63){
        s_red[9][w]=m1; s_red[10][w]=m2; s_red[11][w]=m3; s_red[12][w]=m4;
        s_red[13][w]=vmn; s_red[14][w]=vmx;
        s_red[15][w]=samp_p; s_red[16][w]=samp2_p;
      }
    }
    __syncthreads();   // [B2]  (s_bvp dead for this row past here)

    const int nr = npk > 1 ? npk - 1 : 0;
    const int ns = npk > 2 ? npk - 2 : 0;
    float t_last = (npk >= 1) ? (float)((int)s_pk[npk-1]-(int)s_pk[0]) * INVFS : 0.0f;
    const bool cond = (npk >= 3) && (t_last * 4.0f > 10.0f);

    // ---- prefetch next row (latency hidden under P3) ----
    if (pre){
      const float4* nsrc = (const float4*)(x + (size_t)(row+1) * TLEN + base);
#pragma unroll
      for (int q = 0; q < 5; ++q) vn4[q] = nsrc[q];
    }

    // ---- P3: wave-specialized phase ----
    if (w == 0 || w == 2){
      float srr=0.f, srr2=0.f, shr=0.f, shr2=0.f;
      float hmx = -INFINITY, hmn = INFINITY;
      for (int i = ((w & 2) ? 64 : 0) + lane; i < nr; i += 128){
        float rr = (float)((int)s_pk[i+1]-(int)s_pk[i]) * INVFS;
        srr += rr; srr2 += rr*rr;
        float hr = 60.0f / fmaxf(rr, 1e-6f);
        shr += hr; shr2 += hr*hr;
        hmx = fmaxf(hmx, hr); hmn = fminf(hmn, hr);
      }
      srr = wsum(srr); srr2 = wsum(srr2); shr = wsum(shr); shr2 = wsum(shr2);
      hmx = wmaxr(hmx); hmn = wminr(hmn);
      if (lane == 63){
        s_red[0][w]=srr; s_red[1][w]=srr2; s_red[2][w]=shr; s_red[3][w]=shr2;
        s_red[4][w]=hmx; s_red[5][w]=hmn;
      }
    } else if (w == 1 || w == 3){
      float ssdf=0.f, ssdf2=0.f, c50=0.f;
      for (int i = ((w & 2) ? 64 : 0) + lane; i < ns; i += 128){
        float r0 = (float)((int)s_pk[i+1]-(int)s_pk[i]) * INVFS;
        float r1 = (float)((int)s_pk[i+2]-(int)s_pk[i+1]) * INVFS;
        float d = r1 - r0;
        ssdf += d; ssdf2 += d*d;
        if (fabsf(d) > 0.05f) c50 += 1.0f;
      }
      ssdf = wsum(ssdf); ssdf2 = wsum(ssdf2); c50 = wsum(c50);
      if (lane == 63){
        s_red[6][w]=ssdf; s_red[7][w]=ssdf2; s_red[8][w]=c50;
      }
    } else if (w == 4){
      if (lane < 5){
        const float* rowp = x + (size_t)row * TLEN;
        int limit = npk - 1;
        if (limit > 5) limit = 5;
        float rise = 0.f, fall = 0.f;
        if (lane < limit){
          int pk = (int)s_pk[lane];
          float best = INFINITY; int am = 0;
          for (int off = 0; off < 20; ++off){
            int bi = pk - 20 + off;
            float vv = (bi >= 0) ? rowp[bi] : INFINITY;
            if (vv < best){ best = vv; am = off; }
          }
          rise = (float)(20 - am) * INVFS;
          best = INFINITY; am = 0;
          for (int off = 0; off < 20; ++off){
            int fi = pk + off;
            float vv = (fi < TLEN) ? rowp[fi] : INFINITY;
            if (vv < best){ best = vv; am = off; }
          }
          fall = (float)am * INVFS;
        }
        s_rf[lane] = rise;
        s_rf[5 + lane] = fall;
      }
    } else {
      // wave 5: interp knot table build
      if (cond){
        const int p0 = (int)s_pk[0];
        for (int i = lane; i < npk; i += 64){
          int glo = (i == 0) ? 0 : (((int)s_pk[i] - p0 + 15) >> 4);
          int ghi = (i == npk-1) ? 383 : ((((int)s_pk[i+1] - p0 + 15) >> 4) - 1);
          if (ghi > 383) ghi = 383;
          for (int g = glo; g <= ghi; ++g) s_tbl[g] = (unsigned short)i;
        }
      }
    }

    // ---- stage next row into s_bvp (dead for current row) + its moments ----
    if (pre){
      float4* dst4 = (float4*)(s_bvp + base);
      n1=0.f; n2=0.f; n3=0.f; n4=0.f; nmn=INFINITY; nmx=-INFINITY;
#pragma unroll
      for (int q = 0; q < 5; ++q){
        float4 t4 = vn4[q];
        dst4[q] = t4;
#define NACC(a) { float _a=(a); n1+=_a; float _q=_a*_a; n2+=_q; n3+=_q*_a; n4+=_q*_q; nmn=fminf(nmn,_a); nmx=fmaxf(nmx,_a); }
        NACC(t4.x) NACC(t4.y) NACC(t4.z) NACC(t4.w)
#undef NACC
      }
    }
    __syncthreads();   // [B3]  P3 done + next row staged

    // ---- P4: finalize (tid 128) + interp (all threads) ----
    if (tid == 128){
      float M1=0.f, M2=0.f, M3=0.f, M4=0.f, MN=INFINITY, MX=-INFINITY;
      float Samp=0.f, Samp2=0.f;
#pragma unroll
      for (int j = 0; j < NW; ++j){
        M1 += s_red[9][j]; M2 += s_red[10][j]; M3 += s_red[11][j]; M4 += s_red[12][j];
        MN = fminf(MN, s_red[13][j]); MX = fmaxf(MX, s_red[14][j]);
        Samp += s_red[15][j]; Samp2 += s_red[16][j];
      }
      {
        const float invT = 1.0f / (float)TLEN;
        float mu = M1 * invT;
        float e2 = M2*invT, e3 = M3*invT, e4 = M4*invT;
        float c2 = e2 - mu*mu;
        float c3 = e3 - 3.0f*mu*e2 + 2.0f*mu*mu*mu;
        float c4 = e4 - 4.0f*mu*e3 + 6.0f*mu*mu*e2 - 3.0f*mu*mu*mu*mu;
        float m2c = fmaxf(c2, 1e-30f);
        s_stash[0] = mu;
        s_stash[1] = sqrtf(fmaxf(c2, 0.0f));
        s_stash[2] = c3 / (m2c * sqrtf(m2c));
        s_stash[3] = c4 / (m2c * m2c) - 3.0f;
        s_stash[4] = MN;
        s_stash[5] = MX;
      }
      float Srr  = s_red[0][0]+s_red[0][2], Srr2 = s_red[1][0]+s_red[1][2];
      float Shr  = s_red[2][0]+s_red[2][2], Shr2 = s_red[3][0]+s_red[3][2];
      float Hmx  = fmaxf(s_red[4][0], s_red[4][2]);
      float Hmn  = fminf(s_red[5][0], s_red[5][2]);
      float Ssdf = s_red[6][1]+s_red[6][3];
      float Ssdf2= s_red[7][1]+s_red[7][3];
      float C50  = s_red[8][1]+s_red[8][3];
      const bool g1 = npk >= 1, g2 = npk >= 2, g3 = npk >= 3;
      const float dnr = fmaxf((float)nr, 1.0f);
      const float dns = fmaxf((float)ns, 1.0f);
      const float dnp = fmaxf((float)npk, 1.0f);
      float mean_rr = Srr / dnr;
      float msdf = Ssdf / dns;
      float mhr0 = Shr / dnr;
      float amp_mean = Samp / dnp;
      float amp_std = sqrtf(fmaxf(Samp2/dnp - amp_mean*amp_mean, 0.f));
      s_stash[6]  = g2 ? sqrtf(fmaxf(Srr2/dnr - mean_rr*mean_rr, 0.f)) : 0.f;
      s_stash[7]  = g3 ? sqrtf(fmaxf(Ssdf2/dns, 0.f)) : 0.f;
      s_stash[8]  = g3 ? (C50 / dns * 100.0f) : 0.f;
      s_stash[9]  = g3 ? sqrtf(fmaxf(Ssdf2/dns - msdf*msdf, 0.f)) : 0.f;
      s_stash[10] = g1 ? amp_mean : 0.f;
      s_stash[11] = g1 ? amp_std : 0.f;
      s_stash[12] = (g1 && amp_mean != 0.f) ? amp_std / amp_mean * 100.0f : 0.f;
      s_stash[13] = (g2 && mean_rr > 0.f) ? 60.0f / fmaxf(mean_rr, 1e-6f) : 0.f;
      s_stash[14] = g2 ? sqrtf(fmaxf(Shr2/dnr - mhr0*mhr0, 0.f)) : 0.f;
      s_stash[15] = g2 ? (Hmx - Hmn) : 0.f;
    }

    if (cond){
      const int p0 = (int)s_pk[0];
      const int g = tid;
      float t = (float)g * 0.25f;
      int j = (int)s_tbl[g];
      float vv;
      if (j >= npk-1){
        vv = (float)((int)s_pk[npk-1]-(int)s_pk[npk-2]) * INVFS;
      } else {
        float t0 = (float)((int)s_pk[j]-p0) * INVFS;
        float t1 = (float)((int)s_pk[j+1]-p0) * INVFS;
        float v0 = (j == 0) ? (float)((int)s_pk[1]-(int)s_pk[0]) * INVFS
                            : (float)((int)s_pk[j]-(int)s_pk[j-1]) * INVFS;
        float v1 = (float)((int)s_pk[j+1]-(int)s_pk[j]) * INVFS;
        vv = v0 + (t - t0) * (v1 - v0) / (t1 - t0);
      }
      s_rri[g] = vv;
    }
    __syncthreads();   // [B4]

    // ---- P6: Welch DFT, bins 3..25, quarter-turn rotation, 2-bin interleaved ----
    if (cond){
      float xw0[4], xw1[4];
#pragma unroll
      for (int q = 0; q < 4; ++q){
        int n = lane + (q << 6);
        float hann = 0.5f - 0.5f * hw_cos_rev((float)n * (1.0f/256.0f));
        xw0[q] = s_rri[n]       * hann;   // mean subtraction exact no-op for bins >= 2
        xw1[q] = s_rri[128 + n] * hann;
      }
      float S0a = xw0[0]-xw0[2], S1a = xw0[1]-xw0[3], T0a = xw0[0]+xw0[2], T1a = xw0[1]+xw0[3];
      float S0b = xw1[0]-xw1[2], S1b = xw1[1]-xw1[3], T0b = xw1[0]+xw1[2], T1b = xw1[1]+xw1[3];

#define DFT_PARTIAL(K, R0, I0, R1, I1) {                                    \
      float t_ = (float)(((K) * lane) & 255) * (1.0f/256.0f);               \
      float s_ = hw_sin_rev(t_);                                            \
      float c_ = hw_cos_rev(t_);                                            \
      switch ((K) & 3){                                                     \
        case 0: { float Pa=T0a+T1a, Pb=T0b+T1b;                             \
                  R0=Pa*c_; I0=-Pa*s_; R1=Pb*c_; I1=-Pb*s_; } break;        \
        case 1: { R0 = S0a*c_ - S1a*s_; I0 = -(S0a*s_ + S1a*c_);            \
                  R1 = S0b*c_ - S1b*s_; I1 = -(S0b*s_ + S1b*c_); } break;   \
        case 2: { float Pa=T0a-T1a, Pb=T0b-T1b;                             \
                  R0=Pa*c_; I0=-Pa*s_; R1=Pb*c_; I1=-Pb*s_; } break;        \
        default:{ R0 = S0a*c_ + S1a*s_; I0 = S1a*c_ - S0a*s_;               \
                  R1 = S0b*c_ + S1b*s_; I1 = S1b*c_ - S0b*s_; } break;      \
      }                                                                     \
    }

      for (int kk = w; kk < 23; kk += 2*NW){
        const int kA = kk + 3;
        const bool hasB = (kk + NW) < 23;
        const int kB = kk + NW + 3;
        float a0,a1,a2,a3, b0=0.f,b1=0.f,b2=0.f,b3=0.f;
        DFT_PARTIAL(kA, a0, a1, a2, a3);
        if (hasB) DFT_PARTIAL(kB, b0, b1, b2, b3);
        a0 = wsum(a0); a1 = wsum(a1); a2 = wsum(a2); a3 = wsum(a3);
        b0 = wsum(b0); b1 = wsum(b1); b2 = wsum(b2); b3 = wsum(b3);
        if (lane == 63){
          s_pw[2*kk]   = (a0*a0 + a1*a1) * (2.0f/384.0f);
          s_pw[2*kk+1] = (a2*a2 + a3*a3) * (2.0f/384.0f);
          if (hasB){
            s_pw[2*(kk+NW)]   = (b0*b0 + b1*b1) * (2.0f/384.0f);
            s_pw[2*(kk+NW)+1] = (b2*b2 + b3*b3) * (2.0f/384.0f);
          }
        }
      }
#undef DFT_PARTIAL
    }
    __syncthreads();   // [B5]

    // ---- epilogue (tid 0; other waves proceed into next row's P1) ----
    if (tid == 0){
      const bool g2 = npk >= 2;
      int limit = npk - 1;
      if (limit > 5) limit = 5;
      if (limit < 0) limit = 0;
      const float dlim = fmaxf((float)limit, 1.0f);
      float rise_t = g2 ? (s_rf[0]+s_rf[1]+s_rf[2]+s_rf[3]+s_rf[4]) / dlim : 0.f;
      float fall_t = g2 ? (s_rf[5]+s_rf[6]+s_rf[7]+s_rf[8]+s_rf[9]) / dlim : 0.f;
      float lf = 0.f, hf = 0.f, lfhf = 0.f;
      if (cond){
        const float df = 0.015625f;
        float acc = 0.f;
        for (int k = 3; k <= 9; ++k){
          float pk2 = 0.5f*(s_pw[2*(k-3)] + s_pw[2*(k-3)+1]);
          acc += (k == 3 || k == 9) ? 0.5f*pk2 : pk2;
        }
        lf = acc * df;
        acc = 0.f;
        for (int k = 10; k <= 25; ++k){
          float pk2 = 0.5f*(s_pw[2*(k-3)] + s_pw[2*(k-3)+1]);
          acc += (k == 10 || k == 25) ? 0.5f*pk2 : pk2;
        }
        hf = acc * df;
        if (hf > 0.f) lfhf = lf / fmaxf(hf, 1e-12f);
      }
      float feats[23] = {s_stash[0], s_stash[1], s_stash[2], s_stash[3],
                         s_stash[4], s_stash[5], s_stash[5]-s_stash[4],
                         s_stash[6], s_stash[7], s_stash[8], s_stash[9],
                         lf, hf, lfhf,
                         s_stash[10], s_stash[11], s_stash[12],
                         rise_t, fall_t,
                         s_stash[13], s_stash[14], s_stash[15], (float)npk};
      float* o = out + (size_t)row * 23;
#pragma unroll
      for (int i = 0; i < 23; ++i){
        float vv = feats[i];
        o[i] = (vv == vv && fabsf(vv) != INFINITY) ? vv : 0.0f;
      }
    }

    // ---- rotate next-row regs into current slots ----
    if (pre){
#pragma unroll
      for (int q = 0; q < 5; ++q){
        v[4*q+0]=vn4[q].x; v[4*q+1]=vn4[q].y; v[4*q+2]=vn4[q].z; v[4*q+3]=vn4[q].w;
      }
      m1=n1; m2=n2; m3=n3; m4=n4; vmn=nmn; vmx=nmx;
    }
  }
}

extern "C" void kernel_launch(void* const* d_in, const int* in_sizes, int n_in,
                              void* d_out, int out_size, void* d_ws, size_t ws_size,
                              hipStream_t stream){
  const float* x = (const float*)d_in[0];
  float* out = (float*)d_out;
  const int B = in_sizes[0] / TLEN;
  const int G = (B + 1) / 2;
  bvp_feat_kernel<<<dim3(G), dim3(NB), 0, stream>>>(x, out, B);
}

// Round 16
// 74.317 us; speedup vs baseline: 1.3589x; 1.3589x over previous
//
#include <hip/hip_runtime.h>
#include <math.h>

#define TLEN 7680
#define NB 384
#define NW 6          // waves per block
#define CHUNK 20      // TLEN / NB ; CHUNK > DIST-1=19 => window spans <=1 neighbor chunk
#define KMAX 386      // T//DIST + 2

// DPP cross-lane (VALU pipe, not LDS)
template<int CTRL>
__device__ __forceinline__ float dpp_xfer(float v){
  return __builtin_bit_cast(float, __builtin_amdgcn_update_dpp(
      0, __builtin_bit_cast(int, v), CTRL, 0xF, 0xF, true));
}
// Full 6-level wave64 reduction on pure DPP (rocPRIM pattern):
// 0xB1 xor1, 0x4E xor2, 0x141 xor4, 0x140 xor8 (butterflies within 16-lane rows),
// 0x142 row_bcast15, 0x143 row_bcast31 (cross-row combine).
// RESULT VALID IN LANE 63 ONLY.
__device__ __forceinline__ float wsum(float v){
  v += dpp_xfer<0xB1>(v);
  v += dpp_xfer<0x4E>(v);
  v += dpp_xfer<0x141>(v);
  v += dpp_xfer<0x140>(v);
  v += dpp_xfer<0x142>(v);
  v += dpp_xfer<0x143>(v);
  return v;   // lane 63 = total
}
__device__ __forceinline__ float wmaxr(float v){
  v = fmaxf(v, dpp_xfer<0xB1>(v));
  v = fmaxf(v, dpp_xfer<0x4E>(v));
  v = fmaxf(v, dpp_xfer<0x141>(v));
  v = fmaxf(v, dpp_xfer<0x140>(v));
  v = fmaxf(v, dpp_xfer<0x142>(v));
  v = fmaxf(v, dpp_xfer<0x143>(v));
  return v;   // lane 63 = max
}
__device__ __forceinline__ float wminr(float v){
  v = fminf(v, dpp_xfer<0xB1>(v));
  v = fminf(v, dpp_xfer<0x4E>(v));
  v = fminf(v, dpp_xfer<0x141>(v));
  v = fminf(v, dpp_xfer<0x140>(v));
  v = fminf(v, dpp_xfer<0x142>(v));
  v = fminf(v, dpp_xfer<0x143>(v));
  return v;   // lane 63 = min
}
// hardware trig, input in revolutions in [0,1): D = sin/cos(2*pi*S0)
__device__ __forceinline__ float hw_sin_rev(float t){
  float r; asm("v_sin_f32 %0, %1" : "=v"(r) : "v"(t)); return r;
}
__device__ __forceinline__ float hw_cos_rev(float t){
  float r; asm("v_cos_f32 %0, %1" : "=v"(r) : "v"(t)); return r;
}
__device__ __forceinline__ float hw_rcp(float t){
  float r; asm("v_rcp_f32 %0, %1" : "=v"(r) : "v"(t)); return r;
}

__global__ __launch_bounds__(NB, 4)
void bvp_feat_kernel(const float* __restrict__ x, float* __restrict__ out){
  const int tid = threadIdx.x;
  const int lane = tid & 63;
  const int w = tid >> 6;
  const int b = blockIdx.x;

  __shared__ __align__(16) float s_bvp[TLEN];   // [0:384) -> s_rri, [384:768) -> tbl after [C]
  __shared__ __align__(16) float s_pad[CHUNK];  // -INF dummy halo chunk for edge threads
  __shared__ unsigned short s_pk[KMAX];
  __shared__ float s_red[17][NW];
  __shared__ int   s_wtot[NW];
  __shared__ float s_pw[46];
  __shared__ float s_rf[10];
  __shared__ float s_stash[16];   // uniform per-block scalars, LDS-resident
  float* const s_rri = s_bvp;                                  // bytes [0,1536)
  unsigned short* const tbl = (unsigned short*)(s_bvp + 384);  // bytes [1536,2304)

  const float INVFS = 1.0f/64.0f;

  // ---- P0: chunk-direct load from global + raw moments (kept in regs), stage to LDS ----
  const int base = tid * CHUNK;
  if (tid < CHUNK) s_pad[tid] = -INFINITY;
  float v[CHUNK];
  float m1=0.f, m2=0.f, m3=0.f, m4=0.f, vmn=INFINITY, vmx=-INFINITY;
  {
    const float4* src4 = (const float4*)(x + (size_t)b * TLEN + base);  // 80B/lane, 16B aligned
    float4* dst4 = (float4*)(s_bvp + base);
#pragma unroll
    for (int q = 0; q < 5; ++q){
      float4 t4 = src4[q];
      dst4[q] = t4;
      v[4*q+0]=t4.x; v[4*q+1]=t4.y; v[4*q+2]=t4.z; v[4*q+3]=t4.w;
    }
#pragma unroll
    for (int j = 0; j < CHUNK; ++j){
      float a = v[j]; float q = a*a;
      m1 += a; m2 += q; m3 += q*a; m4 += q*q;
      vmn = fminf(vmn, a); vmx = fmaxf(vmx, a);
    }
  }
  __syncthreads();   // [AB] s_bvp + s_pad staged

  // ---- P1: peak detection — guard-free rolling halo max via -INF pad ----
  const bool has_prev = (tid > 0);
  const bool has_next = (tid < NB-1);
  const float4* nb4 = has_next ? (const float4*)(s_bvp + base + CHUNK) : (const float4*)s_pad;
  const float4* pb4 = has_prev ? (const float4*)(s_bvp + base - CHUNK) : (const float4*)s_pad;
  const float prevs0 = has_prev ? s_bvp[base-1]     : INFINITY;  // +INF kills t=0 peak
  const float next0  = has_next ? s_bvp[base+CHUNK] : INFINITY;  // +INF kills t=TLEN-1 peak
  const float M = vmx;   // own-chunk max == pre-reduction vmx (accumulated over v[0..19])

  unsigned cmask = 0u;
  {
    float pn = M;        // fold "cur >= M" into the rolling max
    float4 nq;
#pragma unroll
    for (int o = 0; o < CHUNK; ++o){
      if (o >= 1){
        const int j = o - 1;
        if ((j & 3) == 0) nq = nb4[j >> 2];
        float nv = ((j&3)==0) ? nq.x : ((j&3)==1) ? nq.y : ((j&3)==2) ? nq.z : nq.w;
        pn = fmaxf(pn, nv);
      }
      float cur = v[o];
      float prevs = (o == 0) ? prevs0 : v[o-1];
      float nxts  = (o == CHUNK-1) ? next0 : v[o+1];
      if (cur > prevs && cur > nxts && cur >= pn)
        cmask |= (1u << o);
    }
  }
  unsigned pmask = 0u;
  int pcnt = 0;
  {
    float sp = -INFINITY;
    float4 pq;
#pragma unroll
    for (int o = CHUNK-1; o >= 0; --o){
      if (((cmask >> o) & 1u) && (v[o] >= sp)){ pmask |= (1u << o); ++pcnt; }
      if (o > 0){
        if ((o & 3) == 3 || o == CHUNK-1) pq = pb4[o >> 2];
        float pv = ((o&3)==0) ? pq.x : ((o&3)==1) ? pq.y : ((o&3)==2) ? pq.z : pq.w;
        sp = fmaxf(sp, pv);
      }
    }
  }

  // wave shuffle scan (needs per-lane values -> keep shfl form)
  int scan = pcnt;
#pragma unroll
  for (int off = 1; off < 64; off <<= 1){
    int t = __shfl_up(scan, off);
    if (lane >= off) scan += t;
  }
  if (lane == 63) s_wtot[w] = scan;
  __syncthreads();   // [B]

  // ---- P2: compact peak indices + amp partials + 8 block-wide reductions ----
  int wbase = 0, total = 0;
#pragma unroll
  for (int j = 0; j < NW; ++j){ if (j < w) wbase += s_wtot[j]; total += s_wtot[j]; }
  const int npk = total < KMAX ? total : KMAX;
  {
    float samp_p = 0.f, samp2_p = 0.f;
    int pos = wbase + scan - pcnt;  // exclusive prefix
    unsigned mm = pmask;
    while (mm){
      int o = __ffs(mm) - 1;
      mm &= mm - 1u;
      if (pos < KMAX){
        s_pk[pos] = (unsigned short)(base + o);
        float a = v[o];
        samp_p += a; samp2_p += a*a;
      }
      ++pos;
    }
    // block-wide reductions folded here: moments + min/max + amp (valid lane 63)
    m1 = wsum(m1); m2 = wsum(m2); m3 = wsum(m3); m4 = wsum(m4);
    vmn = wminr(vmn); vmx = wmaxr(vmx);
    samp_p = wsum(samp_p); samp2_p = wsum(samp2_p);
    if (lane == 63){
      s_red[9][w]=m1; s_red[10][w]=m2; s_red[11][w]=m3; s_red[12][w]=m4;
      s_red[13][w]=vmn; s_red[14][w]=vmx;
      s_red[15][w]=samp_p; s_red[16][w]=samp2_p;
    }
  }
  __syncthreads();   // [C]  (s_bvp raw row dead past here)

  const int nr = npk > 1 ? npk - 1 : 0;
  const int ns = npk > 2 ? npk - 2 : 0;
  float t_last = (npk >= 1) ? (float)((int)s_pk[npk-1]-(int)s_pk[0]) * INVFS : 0.0f;
  const bool cond = (npk >= 3) && (t_last * 4.0f > 10.0f);  // uniform per block

  // ---- P3: wave-specialized phase (rebalanced: 2 waves per stat family) ----
  if (w == 0 || w == 2){
    // rr/hr stats split across waves 0 and 2 (stride 128)
    float srr=0.f, srr2=0.f, shr=0.f, shr2=0.f;
    float hmx = -INFINITY, hmn = INFINITY;
    for (int i = ((w & 2) ? 64 : 0) + lane; i < nr; i += 128){
      float rr = (float)((int)s_pk[i+1]-(int)s_pk[i]) * INVFS;
      srr += rr; srr2 += rr*rr;
      float hr = 60.0f / fmaxf(rr, 1e-6f);
      shr += hr; shr2 += hr*hr;
      hmx = fmaxf(hmx, hr); hmn = fminf(hmn, hr);
    }
    srr = wsum(srr); srr2 = wsum(srr2); shr = wsum(shr); shr2 = wsum(shr2);
    hmx = wmaxr(hmx); hmn = wminr(hmn);
    if (lane == 63){
      s_red[0][w]=srr; s_red[1][w]=srr2; s_red[2][w]=shr; s_red[3][w]=shr2;
      s_red[4][w]=hmx; s_red[5][w]=hmn;
    }
  } else if (w == 1 || w == 3){
    // successive-difference stats split across waves 1 and 3 (stride 128)
    float ssdf=0.f, ssdf2=0.f, c50=0.f;
    for (int i = ((w & 2) ? 64 : 0) + lane; i < ns; i += 128){
      float r0 = (float)((int)s_pk[i+1]-(int)s_pk[i]) * INVFS;
      float r1 = (float)((int)s_pk[i+2]-(int)s_pk[i+1]) * INVFS;
      float d = r1 - r0;
      ssdf += d; ssdf2 += d*d;
      if (fabsf(d) > 0.05f) c50 += 1.0f;
    }
    ssdf = wsum(ssdf); ssdf2 = wsum(ssdf2); c50 = wsum(c50);
    if (lane == 63){
      s_red[6][w]=ssdf; s_red[7][w]=ssdf2; s_red[8][w]=c50;
    }
  } else if (w == 4){
    // rise/fall over first min(npk-1,5) peaks, reading GLOBAL x (L2/L3-hot)
    if (lane < 5){
      const float* row = x + (size_t)b * TLEN;
      int limit = npk - 1;
      if (limit > 5) limit = 5;
      float rise = 0.f, fall = 0.f;
      if (lane < limit){
        int pk = (int)s_pk[lane];
        float best = INFINITY; int am = 0;
        for (int off = 0; off < 20; ++off){
          int bi = pk - 20 + off;
          float vv = (bi >= 0) ? row[bi] : INFINITY;
          if (vv < best){ best = vv; am = off; }
        }
        rise = (float)(20 - am) * INVFS;
        best = INFINITY; am = 0;
        for (int off = 0; off < 20; ++off){
          int fi = pk + off;
          float vv = (fi < TLEN) ? row[fi] : INFINITY;
          if (vv < best){ best = vv; am = off; }
        }
        fall = (float)am * INVFS;
      }
      s_rf[lane] = rise;
      s_rf[5 + lane] = fall;
    }
  } else {
    // wave 5: interp knot table build (tbl aliases dead s_bvp region)
    if (cond){
      const int p0 = (int)s_pk[0];
      for (int i = lane; i < npk; i += 64){
        int glo = (i == 0) ? 0 : (((int)s_pk[i] - p0 + 15) >> 4);
        int ghi = (i == npk-1) ? 383 : ((((int)s_pk[i+1] - p0 + 15) >> 4) - 1);
        if (ghi > 383) ghi = 383;
        for (int g = glo; g <= ghi; ++g) tbl[g] = (unsigned short)i;
      }
    }
  }
  __syncthreads();   // [D]

  // ---- P4: finalize (tid 128) + interp (all threads) ----
  if (tid == 128){
    float M1=0.f, M2=0.f, M3=0.f, M4=0.f, MN=INFINITY, MX=-INFINITY;
    float Samp=0.f, Samp2=0.f;
#pragma unroll
    for (int j = 0; j < NW; ++j){
      M1 += s_red[9][j]; M2 += s_red[10][j]; M3 += s_red[11][j]; M4 += s_red[12][j];
      MN = fminf(MN, s_red[13][j]); MX = fmaxf(MX, s_red[14][j]);
      Samp += s_red[15][j]; Samp2 += s_red[16][j];
    }
    {
      const float invT = 1.0f / (float)TLEN;
      float mu = M1 * invT;
      float e2 = M2*invT, e3 = M3*invT, e4 = M4*invT;
      float c2 = e2 - mu*mu;
      float c3 = e3 - 3.0f*mu*e2 + 2.0f*mu*mu*mu;
      float c4 = e4 - 4.0f*mu*e3 + 6.0f*mu*mu*e2 - 3.0f*mu*mu*mu*mu;
      float m2c = fmaxf(c2, 1e-30f);
      s_stash[0] = mu;
      s_stash[1] = sqrtf(fmaxf(c2, 0.0f));
      s_stash[2] = c3 / (m2c * sqrtf(m2c));
      s_stash[3] = c4 / (m2c * m2c) - 3.0f;
      s_stash[4] = MN;
      s_stash[5] = MX;
    }
    float Srr  = s_red[0][0]+s_red[0][2], Srr2 = s_red[1][0]+s_red[1][2];
    float Shr  = s_red[2][0]+s_red[2][2], Shr2 = s_red[3][0]+s_red[3][2];
    float Hmx  = fmaxf(s_red[4][0], s_red[4][2]);
    float Hmn  = fminf(s_red[5][0], s_red[5][2]);
    float Ssdf = s_red[6][1]+s_red[6][3];
    float Ssdf2= s_red[7][1]+s_red[7][3];
    float C50  = s_red[8][1]+s_red[8][3];
    const bool g1 = npk >= 1, g2 = npk >= 2, g3 = npk >= 3;
    const float dnr = fmaxf((float)nr, 1.0f);
    const float dns = fmaxf((float)ns, 1.0f);
    const float dnp = fmaxf((float)npk, 1.0f);
    float mean_rr = Srr / dnr;
    float msdf = Ssdf / dns;
    float mhr0 = Shr / dnr;
    float amp_mean = Samp / dnp;
    float amp_std = sqrtf(fmaxf(Samp2/dnp - amp_mean*amp_mean, 0.f));
    s_stash[6]  = g2 ? sqrtf(fmaxf(Srr2/dnr - mean_rr*mean_rr, 0.f)) : 0.f;  // sdnn
    s_stash[7]  = g3 ? sqrtf(fmaxf(Ssdf2/dns, 0.f)) : 0.f;                   // rmssd
    s_stash[8]  = g3 ? (C50 / dns * 100.0f) : 0.f;                           // pnn50
    s_stash[9]  = g3 ? sqrtf(fmaxf(Ssdf2/dns - msdf*msdf, 0.f)) : 0.f;       // sdsd
    s_stash[10] = g1 ? amp_mean : 0.f;
    s_stash[11] = g1 ? amp_std : 0.f;
    s_stash[12] = (g1 && amp_mean != 0.f) ? amp_std / amp_mean * 100.0f : 0.f;
    s_stash[13] = (g2 && mean_rr > 0.f) ? 60.0f / fmaxf(mean_rr, 1e-6f) : 0.f; // mean_hr
    s_stash[14] = g2 ? sqrtf(fmaxf(Shr2/dnr - mhr0*mhr0, 0.f)) : 0.f;        // std_hr
    s_stash[15] = g2 ? (Hmx - Hmn) : 0.f;                                    // hr_rng
  }

  if (cond){
    const int p0 = (int)s_pk[0];
    const int g = tid;           // one sample per thread, g in [0,384)
    float t = (float)g * 0.25f;
    int j = (int)tbl[g];
    float vv;
    if (j >= npk-1){
      vv = (float)((int)s_pk[npk-1]-(int)s_pk[npk-2]) * INVFS;  // v_last
    } else {
      float t0 = (float)((int)s_pk[j]-p0) * INVFS;
      float t1 = (float)((int)s_pk[j+1]-p0) * INVFS;
      float v0 = (j == 0) ? (float)((int)s_pk[1]-(int)s_pk[0]) * INVFS
                          : (float)((int)s_pk[j]-(int)s_pk[j-1]) * INVFS;
      float v1 = (float)((int)s_pk[j+1]-(int)s_pk[j]) * INVFS;
      vv = v0 + (t - t0) * (v1 - v0) * hw_rcp(t1 - t0);  // t1-t0 = v1 > 0 always
    }
    s_rri[g] = vv;
  }
  __syncthreads();   // [E]

  // ---- P6: Welch DFT, bins 3..25, quarter-turn rotation, 2-bin interleaved ----
  if (cond){
    float xw0[4], xw1[4];
#pragma unroll
    for (int q = 0; q < 4; ++q){
      int n = lane + (q << 6);
      float hann = 0.5f - 0.5f * hw_cos_rev((float)n * (1.0f/256.0f));
      xw0[q] = s_rri[n]       * hann;   // mean subtraction exact no-op for bins >= 2
      xw1[q] = s_rri[128 + n] * hann;
    }
    float S0a = xw0[0]-xw0[2], S1a = xw0[1]-xw0[3], T0a = xw0[0]+xw0[2], T1a = xw0[1]+xw0[3];
    float S0b = xw1[0]-xw1[2], S1b = xw1[1]-xw1[3], T0b = xw1[0]+xw1[2], T1b = xw1[1]+xw1[3];

#define DFT_PARTIAL(K, R0, I0, R1, I1) {                                    \
      float t_ = (float)(((K) * lane) & 255) * (1.0f/256.0f);               \
      float s_ = hw_sin_rev(t_);                                            \
      float c_ = hw_cos_rev(t_);                                            \
      switch ((K) & 3){                                                     \
        case 0: { float Pa=T0a+T1a, Pb=T0b+T1b;                             \
                  R0=Pa*c_; I0=-Pa*s_; R1=Pb*c_; I1=-Pb*s_; } break;        \
        case 1: { R0 = S0a*c_ - S1a*s_; I0 = -(S0a*s_ + S1a*c_);            \
                  R1 = S0b*c_ - S1b*s_; I1 = -(S0b*s_ + S1b*c_); } break;   \
        case 2: { float Pa=T0a-T1a, Pb=T0b-T1b;                             \
                  R0=Pa*c_; I0=-Pa*s_; R1=Pb*c_; I1=-Pb*s_; } break;        \
        default:{ R0 = S0a*c_ + S1a*s_; I0 = S1a*c_ - S0a*s_;               \
                  R1 = S0b*c_ + S1b*s_; I1 = S1b*c_ - S0b*s_; } break;      \
      }                                                                     \
    }

    for (int kk = w; kk < 23; kk += 2*NW){
      const int kA = kk + 3;
      const bool hasB = (kk + NW) < 23;
      const int kB = kk + NW + 3;
      float a0,a1,a2,a3, b0=0.f,b1=0.f,b2=0.f,b3=0.f;
      DFT_PARTIAL(kA, a0, a1, a2, a3);
      if (hasB) DFT_PARTIAL(kB, b0, b1, b2, b3);
      // 8 independent reduction chains — pure-DPP, valid at lane 63
      a0 = wsum(a0); a1 = wsum(a1); a2 = wsum(a2); a3 = wsum(a3);
      b0 = wsum(b0); b1 = wsum(b1); b2 = wsum(b2); b3 = wsum(b3);
      if (lane == 63){
        s_pw[2*kk]   = (a0*a0 + a1*a1) * (2.0f/384.0f);  // *2 interior-bin * 1/(4*96)
        s_pw[2*kk+1] = (a2*a2 + a3*a3) * (2.0f/384.0f);
        if (hasB){
          s_pw[2*(kk+NW)]   = (b0*b0 + b1*b1) * (2.0f/384.0f);
          s_pw[2*(kk+NW)+1] = (b2*b2 + b3*b3) * (2.0f/384.0f);
        }
      }
    }
#undef DFT_PARTIAL
  }
  __syncthreads();   // [G]

  // ---- epilogue ----
  if (tid == 0){
    const bool g2 = npk >= 2;
    int limit = npk - 1;
    if (limit > 5) limit = 5;
    if (limit < 0) limit = 0;
    const float dlim = fmaxf((float)limit, 1.0f);
    float rise_t = g2 ? (s_rf[0]+s_rf[1]+s_rf[2]+s_rf[3]+s_rf[4]) / dlim : 0.f;
    float fall_t = g2 ? (s_rf[5]+s_rf[6]+s_rf[7]+s_rf[8]+s_rf[9]) / dlim : 0.f;
    float lf = 0.f, hf = 0.f, lfhf = 0.f;
    if (cond){
      const float df = 0.015625f;
      float acc = 0.f;
      for (int k = 3; k <= 9; ++k){
        float pk2 = 0.5f*(s_pw[2*(k-3)] + s_pw[2*(k-3)+1]);
        acc += (k == 3 || k == 9) ? 0.5f*pk2 : pk2;
      }
      lf = acc * df;
      acc = 0.f;
      for (int k = 10; k <= 25; ++k){
        float pk2 = 0.5f*(s_pw[2*(k-3)] + s_pw[2*(k-3)+1]);
        acc += (k == 10 || k == 25) ? 0.5f*pk2 : pk2;
      }
      hf = acc * df;
      if (hf > 0.f) lfhf = lf / fmaxf(hf, 1e-12f);
    }
    float feats[23] = {s_stash[0], s_stash[1], s_stash[2], s_stash[3],
                       s_stash[4], s_stash[5], s_stash[5]-s_stash[4],
                       s_stash[6], s_stash[7], s_stash[8], s_stash[9],
                       lf, hf, lfhf,
                       s_stash[10], s_stash[11], s_stash[12],
                       rise_t, fall_t,
                       s_stash[13], s_stash[14], s_stash[15], (float)npk};
    float* o = out + (size_t)b * 23;
#pragma unroll
    for (int i = 0; i < 23; ++i){
      float vv = feats[i];
      o[i] = (vv == vv && fabsf(vv) != INFINITY) ? vv : 0.0f;  // nan_to_num
    }
  }
}

extern "C" void kernel_launch(void* const* d_in, const int* in_sizes, int n_in,
                              void* d_out, int out_size, void* d_ws, size_t ws_size,
                              hipStream_t stream){
  const float* x = (const float*)d_in[0];
  float* out = (float*)d_out;
  const int B = in_sizes[0] / TLEN;
  bvp_feat_kernel<<<dim3(B), dim3(NB), 0, stream>>>(x, out);
}